// Round 5
// baseline (374.660 us; speedup 1.0000x reference)
//
#include <hip/hip_runtime.h>
#include <hip/hip_bf16.h>

// LSTM: B=16384, T=5, IN=11, H=512. Output = final cell state c [B,H] fp32.
//
// R5 changes vs R4 (249 us; MFMA 25%, L2 B-stream ~133 us was the binding
// pipe, LDS conflicts +4 cyc/read):
//  - rt=4: each wave computes 64 rows x 64 gate-cols -> every B fragment
//    feeds 4 MFMAs; W is read exactly ONCE per block per step (optimal);
//    L2 B traffic halves to 2.3 GB (~66 us floor ~= 71 us MFMA floor).
//  - 8-wave blocks, __launch_bounds__(512,2): 2 waves/SIMD => 256 unified
//    regs/wave. Live set: acc 64 (AGPR) + cacc 64 + 2x(A4+B4)=64 + addr
//    ~= 210 < 256. ks-loop stays `#pragma unroll 1` (R4's anti-spill fix)
//    with an explicit ping-pong 2-stage pipeline (no register copies).
//  - h stored in MFMA A-fragment order [ks][rt][lane*16B]: ds_read_b128 is
//    lane-contiguous (conflict-free), pointer-stepped. h-writes become a
//    16-bit scatter but are 4x rarer than reads.

#define HID   512
#define KSN   17                    // K = 544 = 512 h + 11 x + 1 bias + 20 pad
#define ROWS  64
#define NTHR  512                   // 8 waves
#define HB    (KSN * 4 * 64 * 8)    // halves per frag-ordered h buffer = 34816
#define SMEM_HALFS (2 * HB + 64 * 56)
#define SMEM_BYTES (SMEM_HALFS * 2) // 146432 B

typedef _Float16 f16x8 __attribute__((ext_vector_type(8)));
typedef float f32x4 __attribute__((ext_vector_type(4)));

__device__ __forceinline__ float sigf(float x) {
    return 1.0f / (1.0f + __expf(-x));
}
__device__ __forceinline__ float tanh_fast(float x) {
    return 1.0f - 2.0f / (1.0f + __expf(2.0f * x));
}

// ---------------- prologue: pack W into B-fragment-ordered fp16 tiles -------
// Fragment f = (j*KSN + ks)*4 + g  (g innermost => per-(j,ks) the 4 gate
// frags sit at +0/+1/+2/+3 KB). Lane l holds
// W[col = g*512 + j*16 + (l&15)][k = ks*32 + (l>>4)*8 .. +7], 16 B/lane.
__global__ void pack_w(const float* __restrict__ Wih, const float* __restrict__ Whh,
                       const float* __restrict__ bih, const float* __restrict__ bhh,
                       _Float16* __restrict__ Wt) {
    int tid  = blockIdx.x * 256 + threadIdx.x;
    int frag = tid >> 6;
    int lane = tid & 63;
    if (frag >= 32 * KSN * 4) return;
    int g  = frag & 3;
    int ks = (frag >> 2) % KSN;
    int j  = frag / (4 * KSN);
    int col = g * 512 + j * 16 + (lane & 15);
    int kb  = ks * 32 + ((lane >> 4) << 3);
    _Float16 v[8];
#pragma unroll
    for (int q = 0; q < 8; q++) {
        int k = kb + q;
        float x;
        if (k < 512)      x = Whh[col * 512 + k];
        else if (k < 523) x = Wih[col * 11 + (k - 512)];
        else if (k == 523) x = bih[col] + bhh[col];
        else              x = 0.0f;
        v[q] = (_Float16)x;
    }
    *(f16x8*)(Wt + (size_t)frag * 512 + lane * 8) = *(const f16x8*)v;
}

// ---------------- one recurrent step ----------------------------------------
// Each wave: 64 rows x 4 serial col-quads (j = wave + ji*8) x 4 gates.
// h buffers are A-frag ordered: f16x8 unit index = (ks*4 + rt)*64 + lane.
// KS0=16: only the x/bias K-step (t=0, h==0). WRITE_H=false at t=4.
template <int KS0, bool WRITE_H>
__device__ __forceinline__ void run_step(const _Float16* __restrict__ cur,
                                         _Float16* __restrict__ nxt,
                                         const _Float16* __restrict__ Wt,
                                         float* __restrict__ cacc,
                                         const int wave, const int lane) {
    const int c  = lane & 15;
    const int kq = lane >> 4;
    const f16x8* __restrict__ cur8 = (const f16x8*)cur;
#pragma unroll
    for (int ji = 0; ji < 4; ji++) {
        const int j = wave + ji * 8;
        const f16x8* __restrict__ bp =
            (const f16x8*)Wt + ((size_t)j * KSN + KS0) * 256 + lane;
        const f16x8* __restrict__ ap = cur8 + KS0 * 256 + lane;
        f32x4 acc[4][4];                                   // [row-tile][gate]
#pragma unroll
        for (int rt = 0; rt < 4; rt++)
#pragma unroll
            for (int g = 0; g < 4; g++) {
                f32x4 z = {0.f, 0.f, 0.f, 0.f};
                acc[rt][g] = z;
            }

        f16x8 A0[4], B0[4], A1[4], B1[4];
        auto domfma = [&](f16x8* A, f16x8* B) {
#pragma unroll
            for (int rt = 0; rt < 4; rt++)
#pragma unroll
                for (int g = 0; g < 4; g++)
                    acc[rt][g] = __builtin_amdgcn_mfma_f32_16x16x32_f16(
                        A[rt], B[g], acc[rt][g], 0, 0, 0);
        };

        // prologue: stage 0 = K-step KS0
#pragma unroll
        for (int g = 0; g < 4; g++)  B0[g] = bp[g * 64];
#pragma unroll
        for (int rt = 0; rt < 4; rt++) A0[rt] = ap[rt * 64];

#pragma unroll 1                        // REAL loop (anti-spill, R4 lesson)
        for (int ks = KS0; ks + 1 < KSN; ks += 2) {
            bp += 256; ap += 256;       // -> ks+1
#pragma unroll
            for (int g = 0; g < 4; g++)  B1[g] = bp[g * 64];
#pragma unroll
            for (int rt = 0; rt < 4; rt++) A1[rt] = ap[rt * 64];
            domfma(A0, B0);             // compute ks
            if (ks + 2 < KSN) {
                bp += 256; ap += 256;   // -> ks+2
#pragma unroll
                for (int g = 0; g < 4; g++)  B0[g] = bp[g * 64];
#pragma unroll
                for (int rt = 0; rt < 4; rt++) A0[rt] = ap[rt * 64];
            }
            domfma(A1, B1);             // compute ks+1
        }
        domfma(A0, B0);                 // final odd K-step (KSN-KS0 is odd)

        // gate nonlinearities; C/D layout: col = lane&15, row = (lane>>4)*4+r
#pragma unroll
        for (int rt = 0; rt < 4; rt++) {
#pragma unroll
            for (int r = 0; r < 4; r++) {
                float ig = acc[rt][0][r];
                float fg = acc[rt][1][r];
                float gg = acc[rt][2][r];
                float og = acc[rt][3][r];
                const int ci = ji * 16 + rt * 4 + r;
                float cn = sigf(fg) * cacc[ci] + sigf(ig) * tanh_fast(gg);
                cacc[ci] = cn;
                if (WRITE_H) {
                    float hn = sigf(og) * tanh_fast(cn);
                    // scatter into next buffer's A-frag layout:
                    // k = hcol = j*16+c -> ks'=j>>1, kq2=((j&1)<<1)|(c>>3),
                    // jj=c&7; m' = kq*4+r (row within row-tile rt).
                    const int khi = j >> 1;
                    const int kq2 = ((j & 1) << 1) | (c >> 3);
                    const int idx =
                        ((khi * 4 + rt) * 64 + (kq * 4 + r) + 16 * kq2) * 8 + (c & 7);
                    nxt[idx] = (_Float16)hn;
                }
            }
        }
    }
}

// x_t (11 elems) + nothing else into the ks=16 frag region of a buffer.
__device__ __forceinline__ void xfill(_Float16* __restrict__ nxt,
                                      const _Float16* __restrict__ xlds,
                                      int step, int tid) {
    for (int i = tid; i < 64 * 11; i += NTHR) {
        int row = i / 11, xi = i - row * 11;
        int idx = ((16 * 4 + (row >> 4)) * 64 + ((row & 15) + 16 * (xi >> 3))) * 8
                  + (xi & 7);
        nxt[idx] = xlds[row * 56 + step * 11 + xi];
    }
}

// ---------------- main persistent kernel ------------------------------------
__global__ __launch_bounds__(NTHR, 2)
void lstm_main(const float* __restrict__ ts,
               const _Float16* __restrict__ Wt,
               float* __restrict__ out) {
    extern __shared__ _Float16 smem[];
    _Float16* buf0 = smem;             // frag-ordered h buffers
    _Float16* buf1 = smem + HB;
    _Float16* xlds = smem + 2 * HB;    // [64][56] fp16 staged ts rows
    const int tid  = threadIdx.x;
    const int lane = tid & 63;
    const int wave = tid >> 6;         // 0..7
    const int b0   = blockIdx.x * ROWS;

    // zero both h buffers (covers all pad columns)
    {
        f16x8 z = {(_Float16)0, (_Float16)0, (_Float16)0, (_Float16)0,
                   (_Float16)0, (_Float16)0, (_Float16)0, (_Float16)0};
        for (int i = tid * 8; i < 2 * HB; i += NTHR * 8)
            *(f16x8*)(smem + i) = z;
    }
    // stage this block's time_series rows (coalesced) as fp16
    for (int i = tid; i < 64 * 55; i += NTHR) {
        int row = i / 55, e = i - row * 55;
        xlds[row * 56 + e] = (_Float16)ts[(size_t)(b0 + row) * 55 + e];
    }
    __syncthreads();
    // bias column (k=523 -> ks16, kq2=1, jj=3) = 1.0 in both buffers; x_0 -> buf0
    if (tid < 128) {
        int bsel = tid >> 6, row = tid & 63;
        int idx = ((16 * 4 + (row >> 4)) * 64 + ((row & 15) + 16)) * 8 + 3;
        (bsel ? buf1 : buf0)[idx] = (_Float16)1.0f;
    }
    xfill(buf0, xlds, 0, tid);
    __syncthreads();

    float cacc[64];
#pragma unroll
    for (int i = 0; i < 64; i++) cacc[i] = 0.0f;

    // t = 0: h == 0, only the x/bias K-step contributes
    run_step<16, true>(buf0, buf1, Wt, cacc, wave, lane);
    xfill(buf1, xlds, 1, tid);
    __syncthreads();

    for (int t = 1; t < 4; t++) {
        _Float16* cur = (t & 1) ? buf1 : buf0;
        _Float16* nxt = (t & 1) ? buf0 : buf1;
        run_step<0, true>(cur, nxt, Wt, cacc, wave, lane);
        xfill(nxt, xlds, t + 1, tid);
        __syncthreads();
    }
    // t = 4: no h write needed
    run_step<0, false>(buf0, buf1, Wt, cacc, wave, lane);

    // write final c
    const int c = lane & 15, kq = lane >> 4;
#pragma unroll
    for (int ji = 0; ji < 4; ji++) {
        const int j = wave + ji * 8;
#pragma unroll
        for (int rt = 0; rt < 4; rt++)
#pragma unroll
            for (int r = 0; r < 4; r++)
                out[(size_t)(b0 + rt * 16 + kq * 4 + r) * HID + j * 16 + c] =
                    cacc[ji * 16 + rt * 4 + r];
    }
}

extern "C" void kernel_launch(void* const* d_in, const int* in_sizes, int n_in,
                              void* d_out, int out_size, void* d_ws, size_t ws_size,
                              hipStream_t stream) {
    const float* ts  = (const float*)d_in[0];
    const float* Wih = (const float*)d_in[1];
    const float* Whh = (const float*)d_in[2];
    const float* bih = (const float*)d_in[3];
    const float* bhh = (const float*)d_in[4];
    float* out       = (float*)d_out;
    _Float16* Wt     = (_Float16*)d_ws;   // 2176 frags x 1 KB = 2,228,224 B

    (void)in_sizes; (void)n_in; (void)out_size; (void)ws_size;

    hipFuncSetAttribute(reinterpret_cast<const void*>(lstm_main),
                        hipFuncAttributeMaxDynamicSharedMemorySize, SMEM_BYTES);

    pack_w<<<544, 256, 0, stream>>>(Wih, Whh, bih, bhh, Wt);
    lstm_main<<<256, NTHR, SMEM_BYTES, stream>>>(ts, Wt, out);
}

// Round 6
// 258.155 us; speedup vs baseline: 1.4513x; 1.4513x over previous
//
#include <hip/hip_runtime.h>
#include <hip/hip_bf16.h>

// LSTM: B=16384, T=5, IN=11, H=512. Output = final cell state c [B,H] fp32.
//
// R6 = R4's occupancy + R5's traffic/layout wins, minus R5's mistakes:
//  - 1024 thr / 16 waves per block (4 waves/SIMD, R4's TLP) -- R5 proved
//    2 waves/SIMD + in-wave ping-pong cannot hide L2 latency (16% MfmaUtil).
//  - rt=4, ji=2: each wave 64 rows x 2 col-quads x 4 gates -> W read exactly
//    once per block per step (L2 floor ~66us, R5's win) at 16 waves.
//  - register budget at 16 waves = 128 unified: cacc 32 + acc 64 (AGPR) +
//    B 16 + A (one rt at a time, 4 MFMAs per ds_read_b128) + addr ~8.
//    No manual multi-stage pipeline (R5 lesson), ks-loop `unroll 1`
//    (R4 anti-spill lesson).
//  - h in MFMA A-frag order in LDS: conflict-free ds_read_b128 (R5's win).

#define HID   512
#define KSN   17                    // K = 544 = 512 h + 11 x + 1 bias + 20 pad
#define ROWS  64
#define NTHR  1024                  // 16 waves
#define HB    (KSN * 4 * 64 * 8)    // halves per frag-ordered h buffer = 34816
#define SMEM_HALFS (2 * HB + 64 * 56)
#define SMEM_BYTES (SMEM_HALFS * 2) // 146432 B -> 1 block/CU

typedef _Float16 f16x8 __attribute__((ext_vector_type(8)));
typedef float f32x4 __attribute__((ext_vector_type(4)));

__device__ __forceinline__ float sigf(float x) {
    return 1.0f / (1.0f + __expf(-x));
}
__device__ __forceinline__ float tanh_fast(float x) {
    return 1.0f - 2.0f / (1.0f + __expf(2.0f * x));
}

// ---------------- prologue: pack W into B-fragment-ordered fp16 tiles -------
// Fragment f = (j*KSN + ks)*4 + g  (g innermost). Lane l holds
// W[col = g*512 + j*16 + (l&15)][k = ks*32 + (l>>4)*8 .. +7], 16 B/lane.
__global__ void pack_w(const float* __restrict__ Wih, const float* __restrict__ Whh,
                       const float* __restrict__ bih, const float* __restrict__ bhh,
                       _Float16* __restrict__ Wt) {
    int tid  = blockIdx.x * 256 + threadIdx.x;
    int frag = tid >> 6;
    int lane = tid & 63;
    if (frag >= 32 * KSN * 4) return;
    int g  = frag & 3;
    int ks = (frag >> 2) % KSN;
    int j  = frag / (4 * KSN);
    int col = g * 512 + j * 16 + (lane & 15);
    int kb  = ks * 32 + ((lane >> 4) << 3);
    _Float16 v[8];
#pragma unroll
    for (int q = 0; q < 8; q++) {
        int k = kb + q;
        float x;
        if (k < 512)      x = Whh[col * 512 + k];
        else if (k < 523) x = Wih[col * 11 + (k - 512)];
        else if (k == 523) x = bih[col] + bhh[col];
        else              x = 0.0f;
        v[q] = (_Float16)x;
    }
    *(f16x8*)(Wt + (size_t)frag * 512 + lane * 8) = *(const f16x8*)v;
}

// ---------------- one recurrent step ----------------------------------------
// Wave w handles all 64 rows (rt 0..3) for col-quads j = 2w, 2w+1 x 4 gates.
// h buffers A-frag ordered: f16x8 unit index = (ks*4 + rt)*64 + lane.
// KS0=16: only the x/bias K-step (t=0, h==0). WRITE_H=false at t=4.
template <int KS0, bool WRITE_H>
__device__ __forceinline__ void run_step(const _Float16* __restrict__ cur,
                                         _Float16* __restrict__ nxt,
                                         const _Float16* __restrict__ Wt,
                                         float* __restrict__ cacc,
                                         const int wave, const int lane) {
    const int c  = lane & 15;
    const int kq = lane >> 4;
    const f16x8* __restrict__ cur8 = (const f16x8*)cur;
#pragma unroll
    for (int ji = 0; ji < 2; ji++) {
        const int j = wave * 2 + ji;
        const f16x8* __restrict__ bp =
            (const f16x8*)Wt + ((size_t)j * KSN + KS0) * 256 + lane;
        const f16x8* __restrict__ ap = cur8 + KS0 * 256 + lane;
        f32x4 acc[4][4];                                   // [row-tile][gate]
#pragma unroll
        for (int rt = 0; rt < 4; rt++)
#pragma unroll
            for (int g = 0; g < 4; g++) {
                f32x4 z = {0.f, 0.f, 0.f, 0.f};
                acc[rt][g] = z;
            }

#pragma unroll 1                        // REAL loop (anti-spill, R4 lesson)
        for (int ks = KS0; ks < KSN; ks++) {
            f16x8 B0 = bp[0 * 64];
            f16x8 B1 = bp[1 * 64];
            f16x8 B2 = bp[2 * 64];
            f16x8 B3 = bp[3 * 64];
#pragma unroll
            for (int rt = 0; rt < 4; rt++) {
                f16x8 A = ap[rt * 64];  // one A live at a time: 4 MFMAs/read
                acc[rt][0] = __builtin_amdgcn_mfma_f32_16x16x32_f16(A, B0, acc[rt][0], 0, 0, 0);
                acc[rt][1] = __builtin_amdgcn_mfma_f32_16x16x32_f16(A, B1, acc[rt][1], 0, 0, 0);
                acc[rt][2] = __builtin_amdgcn_mfma_f32_16x16x32_f16(A, B2, acc[rt][2], 0, 0, 0);
                acc[rt][3] = __builtin_amdgcn_mfma_f32_16x16x32_f16(A, B3, acc[rt][3], 0, 0, 0);
            }
            bp += 256;
            ap += 256;
        }

        // gate nonlinearities; C/D layout: col = lane&15, row = (lane>>4)*4+r
#pragma unroll
        for (int rt = 0; rt < 4; rt++) {
#pragma unroll
            for (int r = 0; r < 4; r++) {
                float ig = acc[rt][0][r];
                float fg = acc[rt][1][r];
                float gg = acc[rt][2][r];
                float og = acc[rt][3][r];
                const int ci = ji * 16 + rt * 4 + r;
                float cn = sigf(fg) * cacc[ci] + sigf(ig) * tanh_fast(gg);
                cacc[ci] = cn;
                if (WRITE_H) {
                    float hn = sigf(og) * tanh_fast(cn);
                    // scatter into next buffer's A-frag layout:
                    // k = j*16+c -> ks'=j>>1, kq2=((j&1)<<1)|(c>>3), q=c&7;
                    // row-in-tile m' = kq*4+r.
                    const int khi = j >> 1;
                    const int kq2 = ((j & 1) << 1) | (c >> 3);
                    const int idx =
                        ((khi * 4 + rt) * 64 + (kq * 4 + r) + 16 * kq2) * 8 + (c & 7);
                    nxt[idx] = (_Float16)hn;
                }
            }
        }
    }
}

// x_t (11 elems) into the ks=16 frag region of a buffer (A-frag layout).
__device__ __forceinline__ void xfill(_Float16* __restrict__ nxt,
                                      const _Float16* __restrict__ xlds,
                                      int step, int tid) {
    for (int i = tid; i < 64 * 11; i += NTHR) {
        int row = i / 11, xi = i - row * 11;
        int idx = ((16 * 4 + (row >> 4)) * 64 + ((row & 15) + 16 * (xi >> 3))) * 8
                  + (xi & 7);
        nxt[idx] = xlds[row * 56 + step * 11 + xi];
    }
}

// ---------------- main persistent kernel ------------------------------------
__global__ __launch_bounds__(NTHR, 4)
void lstm_main(const float* __restrict__ ts,
               const _Float16* __restrict__ Wt,
               float* __restrict__ out) {
    extern __shared__ _Float16 smem[];
    _Float16* buf0 = smem;             // frag-ordered h buffers
    _Float16* buf1 = smem + HB;
    _Float16* xlds = smem + 2 * HB;    // [64][56] fp16 staged ts rows
    const int tid  = threadIdx.x;
    const int lane = tid & 63;
    const int wave = tid >> 6;         // 0..15
    const int b0   = blockIdx.x * ROWS;

    // zero both h buffers (covers all pad columns)
    {
        f16x8 z = {(_Float16)0, (_Float16)0, (_Float16)0, (_Float16)0,
                   (_Float16)0, (_Float16)0, (_Float16)0, (_Float16)0};
        for (int i = tid * 8; i < 2 * HB; i += NTHR * 8)
            *(f16x8*)(smem + i) = z;
    }
    // stage this block's time_series rows (coalesced) as fp16
    for (int i = tid; i < 64 * 55; i += NTHR) {
        int row = i / 55, e = i - row * 55;
        xlds[row * 56 + e] = (_Float16)ts[(size_t)(b0 + row) * 55 + e];
    }
    __syncthreads();
    // bias column (k=523 -> ks16, kq2=1, q=3) = 1.0 in both buffers; x_0 -> buf0
    if (tid < 128) {
        int bsel = tid >> 6, row = tid & 63;
        int idx = ((16 * 4 + (row >> 4)) * 64 + ((row & 15) + 16)) * 8 + 3;
        (bsel ? buf1 : buf0)[idx] = (_Float16)1.0f;
    }
    xfill(buf0, xlds, 0, tid);
    __syncthreads();

    float cacc[32];
#pragma unroll
    for (int i = 0; i < 32; i++) cacc[i] = 0.0f;

    // t = 0: h == 0, only the x/bias K-step contributes
    run_step<16, true>(buf0, buf1, Wt, cacc, wave, lane);
    xfill(buf1, xlds, 1, tid);
    __syncthreads();

    for (int t = 1; t < 4; t++) {
        _Float16* cur = (t & 1) ? buf1 : buf0;
        _Float16* nxt = (t & 1) ? buf0 : buf1;
        run_step<0, true>(cur, nxt, Wt, cacc, wave, lane);
        xfill(nxt, xlds, t + 1, tid);
        __syncthreads();
    }
    // t = 4: no h write needed
    run_step<0, false>(buf0, buf1, Wt, cacc, wave, lane);

    // write final c
    const int c = lane & 15, kq = lane >> 4;
#pragma unroll
    for (int ji = 0; ji < 2; ji++) {
        const int j = wave * 2 + ji;
#pragma unroll
        for (int rt = 0; rt < 4; rt++)
#pragma unroll
            for (int r = 0; r < 4; r++)
                out[(size_t)(b0 + rt * 16 + kq * 4 + r) * HID + j * 16 + c] =
                    cacc[ji * 16 + rt * 4 + r];
    }
}

extern "C" void kernel_launch(void* const* d_in, const int* in_sizes, int n_in,
                              void* d_out, int out_size, void* d_ws, size_t ws_size,
                              hipStream_t stream) {
    const float* ts  = (const float*)d_in[0];
    const float* Wih = (const float*)d_in[1];
    const float* Whh = (const float*)d_in[2];
    const float* bih = (const float*)d_in[3];
    const float* bhh = (const float*)d_in[4];
    float* out       = (float*)d_out;
    _Float16* Wt     = (_Float16*)d_ws;   // 2176 frags x 1 KB = 2,228,224 B

    (void)in_sizes; (void)n_in; (void)out_size; (void)ws_size;

    hipFuncSetAttribute(reinterpret_cast<const void*>(lstm_main),
                        hipFuncAttributeMaxDynamicSharedMemorySize, SMEM_BYTES);

    pack_w<<<544, 256, 0, stream>>>(Wih, Whh, bih, bhh, Wt);
    lstm_main<<<256, NTHR, SMEM_BYTES, stream>>>(ts, Wt, out);
}